// Round 8
// baseline (259.332 us; speedup 1.0000x reference)
//
#include <hip/hip_runtime.h>

// B=2,S=2048,H=1024,NH=16,HD=64 fused attention block.
// Round 8: R7 (validated) + XCD-aware block swizzle for BOTH GEMMs:
//          each XCD owns one 4-tile m-band (A stays in its L2; W slice 2MB
//          streams per round). gemm_qkv: A fetched once per XCD across z.
//          attn/cast/LN identical to R7.
#define B_  2
#define S_  2048
#define H_  1024
#define NH_ 16
#define HD_ 64
#define M_  (B_*S_)   // 4096 rows

typedef __attribute__((ext_vector_type(8))) __bf16 bf16x8;
typedef __attribute__((ext_vector_type(4))) float  f32x4;
typedef __attribute__((ext_vector_type(8))) unsigned short us8;
typedef __attribute__((ext_vector_type(4))) float  fl4;

#define GL16(g, l) __builtin_amdgcn_global_load_lds( \
    (const __attribute__((address_space(1))) unsigned int*)(g), \
    (__attribute__((address_space(3))) unsigned int*)(l), 16, 0, 0)

__device__ __forceinline__ unsigned short f2bf(float f) {
    unsigned int u = __float_as_uint(f);
    u += 0x7fffu + ((u >> 16) & 1u);          // round-to-nearest-even
    return (unsigned short)(u >> 16);
}

// ---------------- cast fp32 -> bf16 (x and the 4 weights) ----------------
__global__ __launch_bounds__(256) void cast_kernel(
    const float* __restrict__ x,
    const float* __restrict__ wq, const float* __restrict__ wk,
    const float* __restrict__ wv, const float* __restrict__ wo,
    unsigned short* __restrict__ xb, unsigned short* __restrict__ wb) {
    size_t t  = (size_t)blockIdx.x * 256 + threadIdx.x;
    size_t e0 = t * 4;
    const size_t XN = (size_t)M_ * H_;        // 4M
    const float* src;
    unsigned short* dst;
    if (e0 < XN) { src = x + e0; dst = xb + e0; }
    else {
        size_t j = e0 - XN;                    // 0..4M over 4 weights of 1M
        int w = (int)(j >> 20);
        size_t off = j & ((1u << 20) - 1);
        const float* wp = (w == 0) ? wq : (w == 1) ? wk : (w == 2) ? wv : wo;
        src = wp + off; dst = wb + j;
    }
    fl4 v = *(const fl4*)src;
    ushort4 o;
    o.x = f2bf(v.x); o.y = f2bf(v.y); o.z = f2bf(v.z); o.w = f2bf(v.w);
    *(ushort4*)dst = o;
}

// ---------------- QKV GEMM (128x128 tile, global_load_lds) ----------------
// z==0 -> Q (pre-scaled by 1/8*log2e) ; z==1 -> K ; z==2 -> V transposed.
// XCD swizzle: flat%8 = XCD; XCD x owns m-band x (m-tiles 4x..4x+3) for all
// 3 rounds (round = z). Working set/round: A 1MB + W 2MB < 4MB L2; A-band
// fetched once per XCD across Q/K/V.
__global__ __launch_bounds__(256) void gemm_qkv(
    const unsigned short* __restrict__ xb, const unsigned short* __restrict__ wb,
    const float* __restrict__ bq, const float* __restrict__ bk,
    const float* __restrict__ bv,
    unsigned short* __restrict__ qb, unsigned short* __restrict__ kbuf,
    unsigned short* __restrict__ vT) {
    __shared__ __align__(16) unsigned short As[128 * 64];
    __shared__ __align__(16) unsigned short Bs[128 * 64];
    const int flat = blockIdx.x + 32 * (blockIdx.y + 8 * blockIdx.z); // 0..767
    const int xcd = flat & 7;
    const int sl  = flat >> 3;          // 0..95 within XCD
    const int z   = sl >> 5;            // round = weight slice
    const int idx = sl & 31;            // 4m x 8n within round
    const int m0 = (xcd * 4 + (idx >> 3)) * 128;
    const int n0 = (idx & 7) * 128;
    const unsigned short* W = wb + ((size_t)z << 20);
    const int t = threadIdx.x, lane = t & 63, w = t >> 6;
    const int wm = w >> 1, wn = w & 1, quad = lane >> 4, l16 = lane & 15;
    const int srow = w * 32 + (lane >> 3);
    const int scol = (lane & 7) * 8;
    const unsigned short* ga = xb + (size_t)(m0 + srow) * H_ + scol;
    const unsigned short* gb = W  + (size_t)(n0 + srow) * H_ + scol;

    f32x4 acc[4][4] = {};
    for (int k0 = 0; k0 < H_; k0 += 64) {
        __syncthreads();
#pragma unroll
        for (int j = 0; j < 4; j++) {
            GL16(ga + (size_t)(j * 8) * H_ + k0, &As[(w * 32 + j * 8) * 64]);
            GL16(gb + (size_t)(j * 8) * H_ + k0, &Bs[(w * 32 + j * 8) * 64]);
        }
        __syncthreads();
#pragma unroll
        for (int kk = 0; kk < 64; kk += 32) {
            bf16x8 af[4], bfr[4];
#pragma unroll
            for (int i = 0; i < 4; i++)
                af[i]  = *(const bf16x8*)&As[(wm * 64 + i * 16 + l16) * 64 + kk + quad * 8];
#pragma unroll
            for (int i = 0; i < 4; i++)
                bfr[i] = *(const bf16x8*)&Bs[(wn * 64 + i * 16 + l16) * 64 + kk + quad * 8];
#pragma unroll
            for (int mi = 0; mi < 4; mi++)
#pragma unroll
                for (int ni = 0; ni < 4; ni++)
                    acc[mi][ni] = __builtin_amdgcn_mfma_f32_16x16x32_bf16(
                        af[mi], bfr[ni], acc[mi][ni], 0, 0, 0);
        }
    }
    const float* bias = (z == 0) ? bq : (z == 1) ? bk : bv;
    if (z == 2) {
#pragma unroll
        for (int mi = 0; mi < 4; mi++) {
#pragma unroll
            for (int ni = 0; ni < 4; ni++) {
                int col  = n0 + wn * 64 + ni * 16 + l16;   // h*64+d
                float bval = bias[col];
                int row0 = m0 + wm * 64 + mi * 16 + quad * 4;  // b*2048+s
                int bb = row0 >> 11, s0 = row0 & 2047;
                ushort4 pk;
                pk.x = f2bf(acc[mi][ni][0] + bval);
                pk.y = f2bf(acc[mi][ni][1] + bval);
                pk.z = f2bf(acc[mi][ni][2] + bval);
                pk.w = f2bf(acc[mi][ni][3] + bval);
                *(ushort4*)&vT[((size_t)bb * NH_ * HD_ + col) * S_ + s0] = pk;
            }
        }
    } else {
        unsigned short* out = (z == 0) ? qb : kbuf;
        const float qs = (z == 0) ? 0.18033688f : 1.0f;   // (1/8)*log2(e) folded into Q
#pragma unroll
        for (int mi = 0; mi < 4; mi++) {
#pragma unroll
            for (int ni = 0; ni < 4; ni++) {
                int col = n0 + wn * 64 + ni * 16 + l16;
                float bval = bias[col];
#pragma unroll
                for (int r = 0; r < 4; r++) {
                    int row = m0 + wm * 64 + mi * 16 + quad * 4 + r;
                    out[(size_t)row * H_ + col] = f2bf((acc[mi][ni][r] + bval) * qs);
                }
            }
        }
    }
}

// ---------------- Wo GEMM + bias + residual (128x64 tile, fp32 out) --------
// XCD swizzle: XCD x owns m-band x; its 64 blocks = 4m x 16n.
// Working set: A 1MB + Wo 2MB < 4MB L2.
__global__ __launch_bounds__(256) void gemm_out(
    const unsigned short* __restrict__ ctxb, const unsigned short* __restrict__ wob,
    const float* __restrict__ bo, const float* __restrict__ x,
    float* __restrict__ y) {
    __shared__ __align__(16) unsigned short As[128 * 64];
    __shared__ __align__(16) unsigned short Bs[64 * 64];
    const int flat = blockIdx.x + 32 * blockIdx.y;   // 0..511
    const int xcd = flat & 7;
    const int sl  = flat >> 3;                       // 0..63 within XCD
    const int m0 = (xcd * 4 + (sl >> 4)) * 128;
    const int n0 = (sl & 15) * 64;
    const int t = threadIdx.x, lane = t & 63, w = t >> 6;
    const int quad = lane >> 4, l16 = lane & 15;
    const int l8r = lane >> 3, l8c = (lane & 7) * 8;
    const unsigned short* ga = ctxb + (size_t)(m0 + w * 32 + l8r) * H_ + l8c;
    const unsigned short* gb = wob  + (size_t)(n0 + w * 16 + l8r) * H_ + l8c;

    f32x4 acc[2][4] = {};
    for (int k0 = 0; k0 < H_; k0 += 64) {
        __syncthreads();
#pragma unroll
        for (int j = 0; j < 4; j++)
            GL16(ga + (size_t)(j * 8) * H_ + k0, &As[(w * 32 + j * 8) * 64]);
#pragma unroll
        for (int j = 0; j < 2; j++)
            GL16(gb + (size_t)(j * 8) * H_ + k0, &Bs[(w * 16 + j * 8) * 64]);
        __syncthreads();
#pragma unroll
        for (int kk = 0; kk < 64; kk += 32) {
            bf16x8 af[2], bfr[4];
#pragma unroll
            for (int i = 0; i < 2; i++)
                af[i]  = *(const bf16x8*)&As[(w * 32 + i * 16 + l16) * 64 + kk + quad * 8];
#pragma unroll
            for (int i = 0; i < 4; i++)
                bfr[i] = *(const bf16x8*)&Bs[(i * 16 + l16) * 64 + kk + quad * 8];
#pragma unroll
            for (int mi = 0; mi < 2; mi++)
#pragma unroll
                for (int ni = 0; ni < 4; ni++)
                    acc[mi][ni] = __builtin_amdgcn_mfma_f32_16x16x32_bf16(
                        af[mi], bfr[ni], acc[mi][ni], 0, 0, 0);
        }
    }
#pragma unroll
    for (int mi = 0; mi < 2; mi++) {
#pragma unroll
        for (int ni = 0; ni < 4; ni++) {
            int col = n0 + ni * 16 + l16;
            float bval = bo[col];
#pragma unroll
            for (int r = 0; r < 4; r++) {
                size_t idx = (size_t)(m0 + w * 32 + mi * 16 + quad * 4 + r) * H_ + col;
                y[idx] = acc[mi][ni][r] + bval + x[idx];
            }
        }
    }
}

// ---------------- Flash attention (causal), online softmax -----------------
// 512 wgs (paired q-tiles: uniform 33 steps), XCD-swizzled head locality,
// double-buffered LDS + register prefetch, 1 barrier/step. (R7, unchanged)
__global__ __launch_bounds__(256) void attn_kernel(
    const unsigned short* __restrict__ qb, const unsigned short* __restrict__ kb,
    const unsigned short* __restrict__ vT, unsigned short* __restrict__ ctxb) {
    __shared__ __align__(16) unsigned short Ks[2][64 * 72];   // [key][d]
    __shared__ __align__(16) unsigned short Vt[2][64 * 72];   // [d][key]
    __shared__ __align__(16) unsigned short Ps[64 * 76];
    const int flat = blockIdx.x + (blockIdx.y << 4) + (blockIdx.z << 8);
    const int xcd = flat & 7, slot = flat >> 3;
    const int bh = xcd * 4 + (slot >> 4);
    const int p  = slot & 15;
    const int b = bh >> 4, h = bh & 15;
    const int t = threadIdx.x, lane = t & 63, wid = t >> 6;
    const int quad = lane >> 4, l16 = lane & 15;
    const int sr = t >> 2, sc = (t & 3) * 16;
    const size_t headoff = (size_t)h * HD_;
    const unsigned short* vtb = vT + ((size_t)(b * NH_ + h) * HD_) * S_;  // [d][s]

    for (int half = 0; half < 2; half++) {
        const int qt = half ? (31 - p) : p;
        const int q0 = qt * 64;
        const size_t qrow = (size_t)(b * S_ + q0 + wid * 16 + l16);
        bf16x8 qf0 = *(const bf16x8*)(qb + qrow * H_ + headoff + quad * 8);   // pre-scaled
        bf16x8 qf1 = *(const bf16x8*)(qb + qrow * H_ + headoff + 32 + quad * 8);

        float m_r[4], l_r[4];
        f32x4 o_acc[4] = {};
#pragma unroll
        for (int r = 0; r < 4; r++) { m_r[r] = -1e30f; l_r[r] = 0.f; }

        // preload tile 0 into registers
        const unsigned short* kptr = kb  + (size_t)(b * S_ + sr) * H_ + headoff + sc;
        const unsigned short* vptr = vtb + (size_t)sr * S_ + sc;
        us8 nk0 = *(const us8*)(kptr);
        us8 nk1 = *(const us8*)(kptr + 8);
        us8 nv0 = *(const us8*)(vptr);
        us8 nv1 = *(const us8*)(vptr + 8);
        __syncthreads();   // previous half's LDS readers done
        *(us8*)&Ks[0][sr * 72 + sc]     = nk0;  *(us8*)&Ks[0][sr * 72 + sc + 8] = nk1;
        *(us8*)&Vt[0][sr * 72 + sc]     = nv0;  *(us8*)&Vt[0][sr * 72 + sc + 8] = nv1;
        __syncthreads();

        for (int s = 0; s <= qt; s++) {
            const int buf = s & 1;
            const bool pf = (s < qt);
            if (pf) {   // prefetch next tile into registers (hidden under compute)
                kptr += (size_t)64 * H_;
                vptr += 64;
                nk0 = *(const us8*)(kptr);
                nk1 = *(const us8*)(kptr + 8);
                nv0 = *(const us8*)(vptr);
                nv1 = *(const us8*)(vptr + 8);
            }
            // S = Q K^T  (16 q-rows x 64 keys per wave); scale pre-folded into Q
            f32x4 sacc[4] = {};
#pragma unroll
            for (int kk = 0; kk < 64; kk += 32) {
                bf16x8 af = (kk == 0) ? qf0 : qf1;
#pragma unroll
                for (int nt = 0; nt < 4; nt++) {
                    bf16x8 bf = *(const bf16x8*)&Ks[buf][(nt * 16 + l16) * 72 + kk + quad * 8];
                    sacc[nt] = __builtin_amdgcn_mfma_f32_16x16x32_bf16(af, bf, sacc[nt], 0, 0, 0);
                }
            }
            if (s == qt) {   // causal mask, diagonal tile only (wave-uniform branch)
#pragma unroll
                for (int nt = 0; nt < 4; nt++) {
                    int n = nt * 16 + l16;
#pragma unroll
                    for (int r = 0; r < 4; r++) {
                        int qidx = wid * 16 + quad * 4 + r;
                        if (n > qidx) sacc[nt][r] = -1e30f;
                    }
                }
            }
            // online softmax (base-2), rows across 16-lane groups
#pragma unroll
            for (int r = 0; r < 4; r++) {
                float mx = fmaxf(fmaxf(sacc[0][r], sacc[1][r]), fmaxf(sacc[2][r], sacc[3][r]));
                mx = fmaxf(mx, __shfl_xor(mx, 1));
                mx = fmaxf(mx, __shfl_xor(mx, 2));
                mx = fmaxf(mx, __shfl_xor(mx, 4));
                mx = fmaxf(mx, __shfl_xor(mx, 8));
                float m_new = fmaxf(m_r[r], mx);
                float alpha = exp2f(m_r[r] - m_new);
                float p0 = exp2f(sacc[0][r] - m_new);
                float p1 = exp2f(sacc[1][r] - m_new);
                float p2 = exp2f(sacc[2][r] - m_new);
                float p3 = exp2f(sacc[3][r] - m_new);
                sacc[0][r] = p0; sacc[1][r] = p1; sacc[2][r] = p2; sacc[3][r] = p3;
                float ssum = (p0 + p1) + (p2 + p3);
                ssum += __shfl_xor(ssum, 1);
                ssum += __shfl_xor(ssum, 2);
                ssum += __shfl_xor(ssum, 4);
                ssum += __shfl_xor(ssum, 8);
                l_r[r] = l_r[r] * alpha + ssum;
                m_r[r] = m_new;
#pragma unroll
                for (int dt = 0; dt < 4; dt++) o_acc[dt][r] *= alpha;
            }
            // P: C-layout -> A-layout via LDS (truncating bf16: P in [0,1])
#pragma unroll
            for (int nt = 0; nt < 4; nt++)
#pragma unroll
                for (int r = 0; r < 4; r++)
                    Ps[(wid * 16 + quad * 4 + r) * 76 + nt * 16 + l16] =
                        (unsigned short)(__float_as_uint(sacc[nt][r]) >> 16);
            __threadfence_block();   // order same-wave LDS write->read
            // O += P V
#pragma unroll
            for (int kk = 0; kk < 64; kk += 32) {
                bf16x8 pfr = *(const bf16x8*)&Ps[(wid * 16 + l16) * 76 + kk + quad * 8];
#pragma unroll
                for (int dt = 0; dt < 4; dt++) {
                    bf16x8 vf = *(const bf16x8*)&Vt[buf][(dt * 16 + l16) * 72 + kk + quad * 8];
                    o_acc[dt] = __builtin_amdgcn_mfma_f32_16x16x32_bf16(pfr, vf, o_acc[dt], 0, 0, 0);
                }
            }
            if (pf) {   // publish prefetched tile; single barrier per step
                *(us8*)&Ks[buf ^ 1][sr * 72 + sc]     = nk0;
                *(us8*)&Ks[buf ^ 1][sr * 72 + sc + 8] = nk1;
                *(us8*)&Vt[buf ^ 1][sr * 72 + sc]     = nv0;
                *(us8*)&Vt[buf ^ 1][sr * 72 + sc + 8] = nv1;
                __syncthreads();
            }
        }
        // normalize + store ctx
#pragma unroll
        for (int r = 0; r < 4; r++) {
            float inv = 1.0f / l_r[r];
            size_t row = (size_t)(b * S_ + q0 + wid * 16 + quad * 4 + r);
#pragma unroll
            for (int dt = 0; dt < 4; dt++)
                ctxb[row * H_ + headoff + dt * 16 + l16] = f2bf(o_acc[dt][r] * inv);
        }
    }
}

// ---------------- LayerNorm (1 block per row) ----------------
__global__ __launch_bounds__(256) void ln_kernel(
    const float* __restrict__ y, const float* __restrict__ g,
    const float* __restrict__ bta, float* __restrict__ out) {
    __shared__ float red[8];
    const int row = blockIdx.x, t = threadIdx.x;
    fl4 v = *(const fl4*)(y + (size_t)row * H_ + t * 4);
    float s  = v.x + v.y + v.z + v.w;
    float sq = v.x * v.x + v.y * v.y + v.z * v.z + v.w * v.w;
    for (int m = 1; m < 64; m <<= 1) { s += __shfl_xor(s, m); sq += __shfl_xor(sq, m); }
    const int wid = t >> 6, lane = t & 63;
    if (lane == 0) { red[wid * 2] = s; red[wid * 2 + 1] = sq; }
    __syncthreads();
    s  = red[0] + red[2] + red[4] + red[6];
    sq = red[1] + red[3] + red[5] + red[7];
    float mu   = s * (1.0f / H_);
    float var  = sq * (1.0f / H_) - mu * mu;
    float rstd = rsqrtf(fmaxf(var, 0.f) + 1e-12f);
    fl4 gg = *(const fl4*)(g + t * 4);
    fl4 bb = *(const fl4*)(bta + t * 4);
    fl4 o;
    o.x = (v.x - mu) * rstd * gg.x + bb.x;
    o.y = (v.y - mu) * rstd * gg.y + bb.y;
    o.z = (v.z - mu) * rstd * gg.z + bb.z;
    o.w = (v.w - mu) * rstd * gg.w + bb.w;
    *(fl4*)(out + (size_t)row * H_ + t * 4) = o;
}

extern "C" void kernel_launch(void* const* d_in, const int* in_sizes, int n_in,
                              void* d_out, int out_size, void* d_ws, size_t ws_size,
                              hipStream_t stream) {
    const float* x  = (const float*)d_in[0];
    const float* Wq = (const float*)d_in[1];
    const float* bq = (const float*)d_in[2];
    const float* Wk = (const float*)d_in[3];
    const float* bk = (const float*)d_in[4];
    const float* Wv = (const float*)d_in[5];
    const float* bv = (const float*)d_in[6];
    const float* Wo = (const float*)d_in[7];
    const float* bo = (const float*)d_in[8];
    const float* lg = (const float*)d_in[9];
    const float* lb = (const float*)d_in[10];
    float* out = (float*)d_out;

    const size_t MEG = 1024u * 1024u;
    unsigned short* ws16 = (unsigned short*)d_ws;
    unsigned short* xb   = ws16;                  // 4M bf16
    unsigned short* wb   = ws16 + 4 * MEG;        // 4x1M bf16 (Wq,Wk,Wv,Wo)
    unsigned short* qb   = ws16 + 8 * MEG;
    unsigned short* kb   = ws16 + 12 * MEG;
    unsigned short* vT   = ws16 + 16 * MEG;       // transposed V [b,h,d,s]
    unsigned short* ctxb = ws16 + 20 * MEG;
    float* y = (float*)(ws16 + 24 * MEG);         // 4M fp32; total 64 MB

    cast_kernel<<<8192, 256, 0, stream>>>(x, Wq, Wk, Wv, Wo, xb, wb);
    gemm_qkv<<<dim3(32, 8, 3), 256, 0, stream>>>(xb, wb, bq, bk, bv, qb, kb, vT);
    attn_kernel<<<dim3(16, 16, 2), 256, 0, stream>>>(qb, kb, vT, ctxb);
    gemm_out<<<dim3(32, 16), 256, 0, stream>>>(ctxb, wb + 3 * MEG, bo, x, y);
    ln_kernel<<<4096, 256, 0, stream>>>(y, lg, lb, out);
}

// Round 9
// 216.467 us; speedup vs baseline: 1.1980x; 1.1980x over previous
//
#include <hip/hip_runtime.h>

// B=2,S=2048,H=1024,NH=16,HD=64 fused attention block.
// Round 9: GEMMs reverted to R7 (R8 swizzle regressed). attn restructured:
//          transposed score MFMA (S^T = K Q^T, C[key][q]) so each lane owns
//          ONE query -> softmax reduction = 15 in-lane ops + 2 shuffles
//          (was 4 rows x 4 stages x 2 = 32 shuffles). P packed as b64 writes;
//          PV computes O^T = V^T P; ctx stored as 8B packs.
#define B_  2
#define S_  2048
#define H_  1024
#define NH_ 16
#define HD_ 64
#define M_  (B_*S_)   // 4096 rows

typedef __attribute__((ext_vector_type(8))) __bf16 bf16x8;
typedef __attribute__((ext_vector_type(4))) float  f32x4;
typedef __attribute__((ext_vector_type(8))) unsigned short us8;
typedef __attribute__((ext_vector_type(4))) float  fl4;

#define GL16(g, l) __builtin_amdgcn_global_load_lds( \
    (const __attribute__((address_space(1))) unsigned int*)(g), \
    (__attribute__((address_space(3))) unsigned int*)(l), 16, 0, 0)

__device__ __forceinline__ unsigned short f2bf(float f) {
    unsigned int u = __float_as_uint(f);
    u += 0x7fffu + ((u >> 16) & 1u);          // round-to-nearest-even
    return (unsigned short)(u >> 16);
}

// ---------------- cast fp32 -> bf16 (x and the 4 weights) ----------------
__global__ __launch_bounds__(256) void cast_kernel(
    const float* __restrict__ x,
    const float* __restrict__ wq, const float* __restrict__ wk,
    const float* __restrict__ wv, const float* __restrict__ wo,
    unsigned short* __restrict__ xb, unsigned short* __restrict__ wb) {
    size_t t  = (size_t)blockIdx.x * 256 + threadIdx.x;
    size_t e0 = t * 4;
    const size_t XN = (size_t)M_ * H_;        // 4M
    const float* src;
    unsigned short* dst;
    if (e0 < XN) { src = x + e0; dst = xb + e0; }
    else {
        size_t j = e0 - XN;                    // 0..4M over 4 weights of 1M
        int w = (int)(j >> 20);
        size_t off = j & ((1u << 20) - 1);
        const float* wp = (w == 0) ? wq : (w == 1) ? wk : (w == 2) ? wv : wo;
        src = wp + off; dst = wb + j;
    }
    fl4 v = *(const fl4*)src;
    ushort4 o;
    o.x = f2bf(v.x); o.y = f2bf(v.y); o.z = f2bf(v.z); o.w = f2bf(v.w);
    *(ushort4*)dst = o;
}

// ---------------- QKV GEMM (128x128 tile, global_load_lds) — R7 ------------
// z==0 -> Q (pre-scaled by 1/8*log2e) ; z==1 -> K ; z==2 -> V transposed.
__global__ __launch_bounds__(256) void gemm_qkv(
    const unsigned short* __restrict__ xb, const unsigned short* __restrict__ wb,
    const float* __restrict__ bq, const float* __restrict__ bk,
    const float* __restrict__ bv,
    unsigned short* __restrict__ qb, unsigned short* __restrict__ kbuf,
    unsigned short* __restrict__ vT) {
    __shared__ __align__(16) unsigned short As[128 * 64];
    __shared__ __align__(16) unsigned short Bs[128 * 64];
    const int z = blockIdx.z;
    const unsigned short* W = wb + ((size_t)z << 20);
    const int m0 = blockIdx.x * 128, n0 = blockIdx.y * 128;
    const int t = threadIdx.x, lane = t & 63, w = t >> 6;
    const int wm = w >> 1, wn = w & 1, quad = lane >> 4, l16 = lane & 15;
    const int srow = w * 32 + (lane >> 3);
    const int scol = (lane & 7) * 8;
    const unsigned short* ga = xb + (size_t)(m0 + srow) * H_ + scol;
    const unsigned short* gb = W  + (size_t)(n0 + srow) * H_ + scol;

    f32x4 acc[4][4] = {};
    for (int k0 = 0; k0 < H_; k0 += 64) {
        __syncthreads();
#pragma unroll
        for (int j = 0; j < 4; j++) {
            GL16(ga + (size_t)(j * 8) * H_ + k0, &As[(w * 32 + j * 8) * 64]);
            GL16(gb + (size_t)(j * 8) * H_ + k0, &Bs[(w * 32 + j * 8) * 64]);
        }
        __syncthreads();
#pragma unroll
        for (int kk = 0; kk < 64; kk += 32) {
            bf16x8 af[4], bfr[4];
#pragma unroll
            for (int i = 0; i < 4; i++)
                af[i]  = *(const bf16x8*)&As[(wm * 64 + i * 16 + l16) * 64 + kk + quad * 8];
#pragma unroll
            for (int i = 0; i < 4; i++)
                bfr[i] = *(const bf16x8*)&Bs[(wn * 64 + i * 16 + l16) * 64 + kk + quad * 8];
#pragma unroll
            for (int mi = 0; mi < 4; mi++)
#pragma unroll
                for (int ni = 0; ni < 4; ni++)
                    acc[mi][ni] = __builtin_amdgcn_mfma_f32_16x16x32_bf16(
                        af[mi], bfr[ni], acc[mi][ni], 0, 0, 0);
        }
    }
    const float* bias = (z == 0) ? bq : (z == 1) ? bk : bv;
    if (z == 2) {
#pragma unroll
        for (int mi = 0; mi < 4; mi++) {
#pragma unroll
            for (int ni = 0; ni < 4; ni++) {
                int col  = n0 + wn * 64 + ni * 16 + l16;   // h*64+d
                float bval = bias[col];
                int row0 = m0 + wm * 64 + mi * 16 + quad * 4;  // b*2048+s
                int bb = row0 >> 11, s0 = row0 & 2047;
                ushort4 pk;
                pk.x = f2bf(acc[mi][ni][0] + bval);
                pk.y = f2bf(acc[mi][ni][1] + bval);
                pk.z = f2bf(acc[mi][ni][2] + bval);
                pk.w = f2bf(acc[mi][ni][3] + bval);
                *(ushort4*)&vT[((size_t)bb * NH_ * HD_ + col) * S_ + s0] = pk;
            }
        }
    } else {
        unsigned short* out = (z == 0) ? qb : kbuf;
        const float qs = (z == 0) ? 0.18033688f : 1.0f;   // (1/8)*log2(e) folded into Q
#pragma unroll
        for (int mi = 0; mi < 4; mi++) {
#pragma unroll
            for (int ni = 0; ni < 4; ni++) {
                int col = n0 + wn * 64 + ni * 16 + l16;
                float bval = bias[col];
#pragma unroll
                for (int r = 0; r < 4; r++) {
                    int row = m0 + wm * 64 + mi * 16 + quad * 4 + r;
                    out[(size_t)row * H_ + col] = f2bf((acc[mi][ni][r] + bval) * qs);
                }
            }
        }
    }
}

// ---------------- Wo GEMM + bias + residual (128x64 tile, fp32 out) — R7 ---
__global__ __launch_bounds__(256) void gemm_out(
    const unsigned short* __restrict__ ctxb, const unsigned short* __restrict__ wob,
    const float* __restrict__ bo, const float* __restrict__ x,
    float* __restrict__ y) {
    __shared__ __align__(16) unsigned short As[128 * 64];
    __shared__ __align__(16) unsigned short Bs[64 * 64];
    const int m0 = blockIdx.x * 128, n0 = blockIdx.y * 64;
    const int t = threadIdx.x, lane = t & 63, w = t >> 6;
    const int quad = lane >> 4, l16 = lane & 15;
    const int l8r = lane >> 3, l8c = (lane & 7) * 8;
    const unsigned short* ga = ctxb + (size_t)(m0 + w * 32 + l8r) * H_ + l8c;
    const unsigned short* gb = wob  + (size_t)(n0 + w * 16 + l8r) * H_ + l8c;

    f32x4 acc[2][4] = {};
    for (int k0 = 0; k0 < H_; k0 += 64) {
        __syncthreads();
#pragma unroll
        for (int j = 0; j < 4; j++)
            GL16(ga + (size_t)(j * 8) * H_ + k0, &As[(w * 32 + j * 8) * 64]);
#pragma unroll
        for (int j = 0; j < 2; j++)
            GL16(gb + (size_t)(j * 8) * H_ + k0, &Bs[(w * 16 + j * 8) * 64]);
        __syncthreads();
#pragma unroll
        for (int kk = 0; kk < 64; kk += 32) {
            bf16x8 af[2], bfr[4];
#pragma unroll
            for (int i = 0; i < 2; i++)
                af[i]  = *(const bf16x8*)&As[(w * 32 + i * 16 + l16) * 64 + kk + quad * 8];
#pragma unroll
            for (int i = 0; i < 4; i++)
                bfr[i] = *(const bf16x8*)&Bs[(i * 16 + l16) * 64 + kk + quad * 8];
#pragma unroll
            for (int mi = 0; mi < 2; mi++)
#pragma unroll
                for (int ni = 0; ni < 4; ni++)
                    acc[mi][ni] = __builtin_amdgcn_mfma_f32_16x16x32_bf16(
                        af[mi], bfr[ni], acc[mi][ni], 0, 0, 0);
        }
    }
#pragma unroll
    for (int mi = 0; mi < 2; mi++) {
#pragma unroll
        for (int ni = 0; ni < 4; ni++) {
            int col = n0 + ni * 16 + l16;
            float bval = bo[col];
#pragma unroll
            for (int r = 0; r < 4; r++) {
                size_t idx = (size_t)(m0 + w * 32 + mi * 16 + quad * 4 + r) * H_ + col;
                y[idx] = acc[mi][ni][r] + bval + x[idx];
            }
        }
    }
}

// ---------------- Flash attention (causal), transposed-S softmax -----------
// 512 wgs (paired q-tiles: uniform 33 steps), XCD-swizzled head locality,
// double-buffered LDS + register prefetch, 1 barrier/step.
// S^T = K Q^T -> C[key][q]: lane owns one q (l16), 16 keys (nt,quad,r).
// Softmax: 15 in-lane ops + 2 shuffles per {max,sum}. O^T = V^T P.
__global__ __launch_bounds__(256) void attn_kernel(
    const unsigned short* __restrict__ qb, const unsigned short* __restrict__ kb,
    const unsigned short* __restrict__ vT, unsigned short* __restrict__ ctxb) {
    __shared__ __align__(16) unsigned short Ks[2][64 * 72];   // [key][d]
    __shared__ __align__(16) unsigned short Vt[2][64 * 72];   // [d][key]
    __shared__ __align__(16) unsigned short Ps[64 * 76];      // [q][key] per wave
    const int flat = blockIdx.x + (blockIdx.y << 4) + (blockIdx.z << 8);
    const int xcd = flat & 7, slot = flat >> 3;
    const int bh = xcd * 4 + (slot >> 4);
    const int p  = slot & 15;
    const int b = bh >> 4, h = bh & 15;
    const int t = threadIdx.x, lane = t & 63, wid = t >> 6;
    const int quad = lane >> 4, l16 = lane & 15;
    const int sr = t >> 2, sc = (t & 3) * 16;
    const size_t headoff = (size_t)h * HD_;
    const unsigned short* vtb = vT + ((size_t)(b * NH_ + h) * HD_) * S_;  // [d][s]

    for (int half = 0; half < 2; half++) {
        const int qt = half ? (31 - p) : p;
        const int q0 = qt * 64;
        // Q fragment: lane l16 holds query q0+wid*16+l16, d = quad*8+j (B-operand)
        const size_t qrow = (size_t)(b * S_ + q0 + wid * 16 + l16);
        bf16x8 qf0 = *(const bf16x8*)(qb + qrow * H_ + headoff + quad * 8);   // pre-scaled
        bf16x8 qf1 = *(const bf16x8*)(qb + qrow * H_ + headoff + 32 + quad * 8);

        float m_r = -1e30f, l_r = 0.f;    // per-lane (one query)
        f32x4 o_acc[4] = {};              // O^T: d = dt*16+quad*4+r, q = l16

        // preload tile 0 into registers
        const unsigned short* kptr = kb  + (size_t)(b * S_ + sr) * H_ + headoff + sc;
        const unsigned short* vptr = vtb + (size_t)sr * S_ + sc;
        us8 nk0 = *(const us8*)(kptr);
        us8 nk1 = *(const us8*)(kptr + 8);
        us8 nv0 = *(const us8*)(vptr);
        us8 nv1 = *(const us8*)(vptr + 8);
        __syncthreads();   // previous half's LDS readers done
        *(us8*)&Ks[0][sr * 72 + sc]     = nk0;  *(us8*)&Ks[0][sr * 72 + sc + 8] = nk1;
        *(us8*)&Vt[0][sr * 72 + sc]     = nv0;  *(us8*)&Vt[0][sr * 72 + sc + 8] = nv1;
        __syncthreads();

        for (int s = 0; s <= qt; s++) {
            const int buf = s & 1;
            const bool pf = (s < qt);
            if (pf) {   // prefetch next tile into registers (hidden under compute)
                kptr += (size_t)64 * H_;
                vptr += 64;
                nk0 = *(const us8*)(kptr);
                nk1 = *(const us8*)(kptr + 8);
                nv0 = *(const us8*)(vptr);
                nv1 = *(const us8*)(vptr + 8);
            }
            // S^T = K Q^T: A = K (m=key), B = Q (n=q) -> C[key][q]
            f32x4 sacc[4] = {};
#pragma unroll
            for (int kk = 0; kk < 64; kk += 32) {
                bf16x8 bq_ = (kk == 0) ? qf0 : qf1;
#pragma unroll
                for (int nt = 0; nt < 4; nt++) {
                    bf16x8 ak = *(const bf16x8*)&Ks[buf][(nt * 16 + l16) * 72 + kk + quad * 8];
                    sacc[nt] = __builtin_amdgcn_mfma_f32_16x16x32_bf16(ak, bq_, sacc[nt], 0, 0, 0);
                }
            }
            if (s == qt) {   // causal mask, diagonal tile only (wave-uniform branch)
#pragma unroll
                for (int nt = 0; nt < 4; nt++) {
#pragma unroll
                    for (int r = 0; r < 4; r++) {
                        int key = nt * 16 + quad * 4 + r;
                        if (key > wid * 16 + l16) sacc[nt][r] = -1e30f;
                    }
                }
            }
            // online softmax (base-2): in-lane over 16 keys + 2 cross-quad shuffles
            float mx = sacc[0][0];
#pragma unroll
            for (int nt = 0; nt < 4; nt++)
#pragma unroll
                for (int r = 0; r < 4; r++) mx = fmaxf(mx, sacc[nt][r]);
            mx = fmaxf(mx, __shfl_xor(mx, 16));
            mx = fmaxf(mx, __shfl_xor(mx, 32));
            float m_new = fmaxf(m_r, mx);
            float alpha = exp2f(m_r - m_new);
            float ss = 0.f;
#pragma unroll
            for (int nt = 0; nt < 4; nt++) {
                ushort4 pk;
                float p0 = exp2f(sacc[nt][0] - m_new);
                float p1 = exp2f(sacc[nt][1] - m_new);
                float p2 = exp2f(sacc[nt][2] - m_new);
                float p3 = exp2f(sacc[nt][3] - m_new);
                ss += (p0 + p1) + (p2 + p3);
                pk.x = (unsigned short)(__float_as_uint(p0) >> 16);
                pk.y = (unsigned short)(__float_as_uint(p1) >> 16);
                pk.z = (unsigned short)(__float_as_uint(p2) >> 16);
                pk.w = (unsigned short)(__float_as_uint(p3) >> 16);
                // Ps[q][key]: q = wid*16+l16, keys nt*16+quad*4..+3 (8B write)
                *(ushort4*)&Ps[(wid * 16 + l16) * 76 + nt * 16 + quad * 4] = pk;
            }
            ss += __shfl_xor(ss, 16);
            ss += __shfl_xor(ss, 32);
            l_r = l_r * alpha + ss;
            m_r = m_new;
#pragma unroll
            for (int dt = 0; dt < 4; dt++)
#pragma unroll
                for (int r = 0; r < 4; r++) o_acc[dt][r] *= alpha;
            __threadfence_block();   // order same-wave LDS write->read
            // O^T += V^T P: A = V^T (m=d), B = P (n=q)
#pragma unroll
            for (int kk = 0; kk < 64; kk += 32) {
                bf16x8 pfr = *(const bf16x8*)&Ps[(wid * 16 + l16) * 76 + kk + quad * 8];
#pragma unroll
                for (int dt = 0; dt < 4; dt++) {
                    bf16x8 vf = *(const bf16x8*)&Vt[buf][(dt * 16 + l16) * 72 + kk + quad * 8];
                    o_acc[dt] = __builtin_amdgcn_mfma_f32_16x16x32_bf16(vf, pfr, o_acc[dt], 0, 0, 0);
                }
            }
            if (pf) {   // publish prefetched tile; single barrier per step
                *(us8*)&Ks[buf ^ 1][sr * 72 + sc]     = nk0;
                *(us8*)&Ks[buf ^ 1][sr * 72 + sc + 8] = nk1;
                *(us8*)&Vt[buf ^ 1][sr * 72 + sc]     = nv0;
                *(us8*)&Vt[buf ^ 1][sr * 72 + sc + 8] = nv1;
                __syncthreads();
            }
        }
        // normalize + store ctx: lane q = l16, d = dt*16+quad*4+r (8B packs)
        {
            float inv = 1.0f / l_r;
            size_t row = (size_t)(b * S_ + q0 + wid * 16 + l16);
#pragma unroll
            for (int dt = 0; dt < 4; dt++) {
                ushort4 pk;
                pk.x = f2bf(o_acc[dt][0] * inv);
                pk.y = f2bf(o_acc[dt][1] * inv);
                pk.z = f2bf(o_acc[dt][2] * inv);
                pk.w = f2bf(o_acc[dt][3] * inv);
                *(ushort4*)&ctxb[row * H_ + headoff + dt * 16 + quad * 4] = pk;
            }
        }
    }
}

// ---------------- LayerNorm (1 block per row) ----------------
__global__ __launch_bounds__(256) void ln_kernel(
    const float* __restrict__ y, const float* __restrict__ g,
    const float* __restrict__ bta, float* __restrict__ out) {
    __shared__ float red[8];
    const int row = blockIdx.x, t = threadIdx.x;
    fl4 v = *(const fl4*)(y + (size_t)row * H_ + t * 4);
    float s  = v.x + v.y + v.z + v.w;
    float sq = v.x * v.x + v.y * v.y + v.z * v.z + v.w * v.w;
    for (int m = 1; m < 64; m <<= 1) { s += __shfl_xor(s, m); sq += __shfl_xor(sq, m); }
    const int wid = t >> 6, lane = t & 63;
    if (lane == 0) { red[wid * 2] = s; red[wid * 2 + 1] = sq; }
    __syncthreads();
    s  = red[0] + red[2] + red[4] + red[6];
    sq = red[1] + red[3] + red[5] + red[7];
    float mu   = s * (1.0f / H_);
    float var  = sq * (1.0f / H_) - mu * mu;
    float rstd = rsqrtf(fmaxf(var, 0.f) + 1e-12f);
    fl4 gg = *(const fl4*)(g + t * 4);
    fl4 bb = *(const fl4*)(bta + t * 4);
    fl4 o;
    o.x = (v.x - mu) * rstd * gg.x + bb.x;
    o.y = (v.y - mu) * rstd * gg.y + bb.y;
    o.z = (v.z - mu) * rstd * gg.z + bb.z;
    o.w = (v.w - mu) * rstd * gg.w + bb.w;
    *(fl4*)(out + (size_t)row * H_ + t * 4) = o;
}

extern "C" void kernel_launch(void* const* d_in, const int* in_sizes, int n_in,
                              void* d_out, int out_size, void* d_ws, size_t ws_size,
                              hipStream_t stream) {
    const float* x  = (const float*)d_in[0];
    const float* Wq = (const float*)d_in[1];
    const float* bq = (const float*)d_in[2];
    const float* Wk = (const float*)d_in[3];
    const float* bk = (const float*)d_in[4];
    const float* Wv = (const float*)d_in[5];
    const float* bv = (const float*)d_in[6];
    const float* Wo = (const float*)d_in[7];
    const float* bo = (const float*)d_in[8];
    const float* lg = (const float*)d_in[9];
    const float* lb = (const float*)d_in[10];
    float* out = (float*)d_out;

    const size_t MEG = 1024u * 1024u;
    unsigned short* ws16 = (unsigned short*)d_ws;
    unsigned short* xb   = ws16;                  // 4M bf16
    unsigned short* wb   = ws16 + 4 * MEG;        // 4x1M bf16 (Wq,Wk,Wv,Wo)
    unsigned short* qb   = ws16 + 8 * MEG;
    unsigned short* kb   = ws16 + 12 * MEG;
    unsigned short* vT   = ws16 + 16 * MEG;       // transposed V [b,h,d,s]
    unsigned short* ctxb = ws16 + 20 * MEG;
    float* y = (float*)(ws16 + 24 * MEG);         // 4M fp32; total 64 MB

    cast_kernel<<<8192, 256, 0, stream>>>(x, Wq, Wk, Wv, Wo, xb, wb);
    gemm_qkv<<<dim3(32, 8, 3), 256, 0, stream>>>(xb, wb, bq, bk, bv, qb, kb, vT);
    attn_kernel<<<dim3(16, 16, 2), 256, 0, stream>>>(qb, kb, vT, ctxb);
    gemm_out<<<dim3(32, 16), 256, 0, stream>>>(ctxb, wb + 3 * MEG, bo, x, y);
    ln_kernel<<<4096, 256, 0, stream>>>(y, lg, lb, out);
}